// Round 1
// baseline (2560.519 us; speedup 1.0000x reference)
//
#include <hip/hip_runtime.h>
#include <hip/hip_bf16.h>

// Problem constants
constexpr int B_ = 2;
constexpr int C_ = 256;
constexpr int S_TOT = 48 * 48;   // 2304
constexpr int HEADS_ = 8;
#define SQRT_DH 5.656854249492380195206754896838f

// ---------------------------------------------------------------------------
// Kernel 1: MLP layer  out[b][s][co] = relu( sum_ci in[b][s][ci]*W[ci][co] + bias[co] )
// IN_MODE 0: in is [B][C][S] (x / ref layout, channel-major)
// IN_MODE 1: in is [B][S][C] (row-major hidden)
// grid (72, B), block 256, 32 s-rows per block, 1 co per thread
// ---------------------------------------------------------------------------
template<int IN_MODE>
__global__ __launch_bounds__(256) void k_mlp(const float* __restrict__ in,
                                             const float* __restrict__ Wm,
                                             const float* __restrict__ bias,
                                             float* __restrict__ out) {
  __shared__ __align__(16) float in_s[32][260];
  const int tid = threadIdx.x;
  const int s0 = blockIdx.x * 32;
  const int b  = blockIdx.y;

  if (IN_MODE == 0) {
    for (int idx = tid; idx < 32 * 256; idx += 256) {
      int ci = idx >> 5, r = idx & 31;
      in_s[r][ci] = in[((size_t)b * C_ + ci) * S_TOT + s0 + r];
    }
  } else {
    for (int idx = tid; idx < 32 * 256; idx += 256) {
      int r = idx >> 8, ci = idx & 255;
      in_s[r][ci] = in[((size_t)b * S_TOT + s0 + r) * C_ + ci];
    }
  }
  __syncthreads();

  const int co = tid;
  float acc[32];
#pragma unroll
  for (int r = 0; r < 32; ++r) acc[r] = 0.f;

  for (int c4 = 0; c4 < 64; ++c4) {
    const float w0 = Wm[(c4 * 4 + 0) * C_ + co];
    const float w1 = Wm[(c4 * 4 + 1) * C_ + co];
    const float w2 = Wm[(c4 * 4 + 2) * C_ + co];
    const float w3 = Wm[(c4 * 4 + 3) * C_ + co];
#pragma unroll
    for (int r = 0; r < 32; ++r) {
      float4 a = *(const float4*)&in_s[r][c4 * 4];
      acc[r] = fmaf(a.x, w0, fmaf(a.y, w1, fmaf(a.z, w2, fmaf(a.w, w3, acc[r]))));
    }
  }

  const float bi = bias[co];
#pragma unroll 4
  for (int r = 0; r < 32; ++r) {
    out[((size_t)b * S_TOT + s0 + r) * C_ + co] = fmaxf(acc[r] + bi, 0.f);
  }
}

// ---------------------------------------------------------------------------
// Kernel 2: fused scores = (Q.K^T)/sqrt(dh) for all 8 heads, top-1-over-heads
// masking, masked-score write to probs region, online per-row softmax stats.
// grid (36 i-tiles, 4 j-chunks, B), block 256, 64x64 tile, micro 4x4/thread.
// LDS 128 KiB (q 64x256 + k 64x256, XOR-swizzled float4 units).
// ---------------------------------------------------------------------------
__global__ __launch_bounds__(256, 1) void k_scores(const float* __restrict__ Qp,
                                                   const float* __restrict__ Kp,
                                                   float* __restrict__ probs,
                                                   float* __restrict__ st_m,
                                                   float* __restrict__ st_z) {
  __shared__ __align__(16) float q_s[64 * 256];
  __shared__ __align__(16) float k_s[64 * 256];
  const int tid = threadIdx.x;
  const int i0 = blockIdx.x * 64;
  const int js = blockIdx.y;          // 0..3, chunk of 576 j's
  const int b  = blockIdx.z;
  const int jbase = js * 576;
  const int iq = tid >> 4;            // 0..15
  const int jq = tid & 15;            // 0..15

  // stage Q tile (swizzled: float4 unit c4 -> c4 ^ (row&7))
  for (int idx = tid; idx < 64 * 64; idx += 256) {
    int r = idx >> 6, c4 = idx & 63;
    float4 v = *(const float4*)(Qp + ((size_t)b * S_TOT + i0 + r) * C_ + c4 * 4);
    *(float4*)&q_s[r * 256 + ((c4 ^ (r & 7)) << 2)] = v;
  }

  float m_st[4][8], z_st[4][8];
#pragma unroll
  for (int v = 0; v < 4; ++v)
#pragma unroll
    for (int h = 0; h < 8; ++h) { m_st[v][h] = -1e18f; z_st[v][h] = 0.f; }

  for (int jt = 0; jt < 9; ++jt) {
    const int j0 = jbase + jt * 64;
    __syncthreads();
    for (int idx = tid; idx < 64 * 64; idx += 256) {
      int r = idx >> 6, c4 = idx & 63;
      float4 v = *(const float4*)(Kp + ((size_t)b * S_TOT + j0 + r) * C_ + c4 * 4);
      *(float4*)&k_s[r * 256 + ((c4 ^ (r & 7)) << 2)] = v;
    }
    __syncthreads();

    float sacc[4][4][8];
#pragma unroll
    for (int v = 0; v < 4; ++v)
#pragma unroll
      for (int u = 0; u < 4; ++u)
#pragma unroll
        for (int h = 0; h < 8; ++h) sacc[v][u][h] = 0.f;

#pragma unroll
    for (int h = 0; h < 8; ++h) {
#pragma unroll
      for (int cc = 0; cc < 8; ++cc) {
        const int c4g = h * 8 + cc;
        float4 qv[4], kv[4];
#pragma unroll
        for (int v = 0; v < 4; ++v) {
          int r = iq + 16 * v;
          qv[v] = *(const float4*)&q_s[r * 256 + ((c4g ^ (r & 7)) << 2)];
        }
#pragma unroll
        for (int u = 0; u < 4; ++u) {
          int r = jq + 16 * u;
          kv[u] = *(const float4*)&k_s[r * 256 + ((c4g ^ (r & 7)) << 2)];
        }
#pragma unroll
        for (int v = 0; v < 4; ++v)
#pragma unroll
          for (int u = 0; u < 4; ++u) {
            sacc[v][u][h] = fmaf(qv[v].x, kv[u].x,
                             fmaf(qv[v].y, kv[u].y,
                               fmaf(qv[v].z, kv[u].z,
                                 fmaf(qv[v].w, kv[u].w, sacc[v][u][h]))));
          }
      }
    }

    // epilogue: scale, head-max threshold, mask, store, online stats
#pragma unroll
    for (int v = 0; v < 4; ++v) {
      const int i = i0 + iq + 16 * v;
#pragma unroll
      for (int u = 0; u < 4; ++u) {
        const int j = j0 + jq + 16 * u;
        float sc[8];
        float thr = -1e30f;
#pragma unroll
        for (int h = 0; h < 8; ++h) {
          sc[h] = sacc[v][u][h] / SQRT_DH;
          thr = fmaxf(thr, sc[h]);
        }
#pragma unroll
        for (int h = 0; h < 8; ++h) {
          float mv = sc[h] < thr ? -1e18f : sc[h];
          probs[((size_t)((b * 8 + h) * S_TOT + i)) * S_TOT + j] = mv;
          float om = m_st[v][h];
          float nm = fmaxf(om, mv);
          z_st[v][h] = fmaf(z_st[v][h], __expf(om - nm), __expf(mv - nm));
          m_st[v][h] = nm;
        }
      }
    }
  }

  // reduce stats across the 16 jq lanes (consecutive lanes within wave)
#pragma unroll
  for (int v = 0; v < 4; ++v) {
#pragma unroll
    for (int h = 0; h < 8; ++h) {
      float m = m_st[v][h], z = z_st[v][h];
#pragma unroll
      for (int off = 8; off >= 1; off >>= 1) {
        float m2 = __shfl_xor(m, off, 16);
        float z2 = __shfl_xor(z, off, 16);
        float nm = fmaxf(m, m2);
        z = fmaf(z, __expf(m - nm), z2 * __expf(m2 - nm));
        m = nm;
      }
      if (jq == 0) {
        const int i = i0 + iq + 16 * v;
        size_t sidx = ((size_t)(js * B_ + b) * HEADS_ + h) * S_TOT + i;
        st_m[sidx] = m;
        st_z[sidx] = z;
      }
    }
  }
}

// ---------------------------------------------------------------------------
// Kernel 3: finalize probs = exp(s - m)/Z (in-place in d_out probs region),
// and ctx = probs @ V, written in [B][C][S] spatial layout for the convs.
// grid (144 i-tiles, 8 heads, B), block 256.
// ---------------------------------------------------------------------------
__global__ __launch_bounds__(256) void k_probs_pv(const float* __restrict__ Vp,
                                                  const float* __restrict__ st_m,
                                                  const float* __restrict__ st_z,
                                                  float* __restrict__ probs,
                                                  float* __restrict__ ctx) {
  __shared__ __align__(16) float v_s[32][36];
  __shared__ __align__(16) float p_s[16][36];
  __shared__ float row_m[16], row_iz[16];
  __shared__ __align__(16) float ctx_red[8][16][32];
  const int tid = threadIdx.x;
  const int i0 = blockIdx.x * 16;
  const int h  = blockIdx.y;
  const int b  = blockIdx.z;

  if (tid < 16) {
    const int i = i0 + tid;
    float mm[4], zz[4];
#pragma unroll
    for (int js = 0; js < 4; ++js) {
      size_t sidx = ((size_t)(js * B_ + b) * HEADS_ + h) * S_TOT + i;
      mm[js] = st_m[sidx];
      zz[js] = st_z[sidx];
    }
    float M = fmaxf(fmaxf(mm[0], mm[1]), fmaxf(mm[2], mm[3]));
    float Z = zz[0] * __expf(mm[0] - M) + zz[1] * __expf(mm[1] - M) +
              zz[2] * __expf(mm[2] - M) + zz[3] * __expf(mm[3] - M);
    row_m[tid] = M;
    row_iz[tid] = 1.0f / Z;
  }
  __syncthreads();

  const int il = tid >> 5;        // phase A: 0..7
  const int jl = tid & 31;
  const int d4 = tid & 7;         // phase B
  const int ip = (tid >> 3) & 3;
  const int jp = tid >> 5;        // 0..7

  float4 acc[4];
#pragma unroll
  for (int r = 0; r < 4; ++r) acc[r] = make_float4(0.f, 0.f, 0.f, 0.f);

  float* pbase = probs + ((size_t)(b * 8 + h) * S_TOT + i0) * S_TOT;
  const float* vbase = Vp + (size_t)b * S_TOT * C_ + h * 32;

  for (int j0 = 0; j0 < S_TOT; j0 += 32) {
    __syncthreads();
    // stage V tile [32 j][32 d]
#pragma unroll
    for (int k = 0; k < 4; ++k) {
      int e = tid + k * 256;
      int r = e >> 5, d = e & 31;
      v_s[r][d] = vbase[(size_t)(j0 + r) * C_ + d];
    }
    // phase A: probs for rows il, il+8
#pragma unroll
    for (int rr = 0; rr < 2; ++rr) {
      int r = il + rr * 8;
      size_t off = (size_t)r * S_TOT + j0 + jl;
      float sv = pbase[off];
      float p = __expf(sv - row_m[r]) * row_iz[r];
      pbase[off] = p;
      p_s[r][jl] = p;
    }
    __syncthreads();
    // phase B: acc += P * V  (thread: rows ip+4*rq, cols d4*4.., j's jp*4..+3)
    float4 v4[4];
#pragma unroll
    for (int jj = 0; jj < 4; ++jj) v4[jj] = *(const float4*)&v_s[jp * 4 + jj][d4 * 4];
#pragma unroll
    for (int rq = 0; rq < 4; ++rq) {
      int r = ip + rq * 4;
      float4 p4 = *(const float4*)&p_s[r][jp * 4];
      acc[rq].x = fmaf(p4.x, v4[0].x, fmaf(p4.y, v4[1].x, fmaf(p4.z, v4[2].x, fmaf(p4.w, v4[3].x, acc[rq].x))));
      acc[rq].y = fmaf(p4.x, v4[0].y, fmaf(p4.y, v4[1].y, fmaf(p4.z, v4[2].y, fmaf(p4.w, v4[3].y, acc[rq].y))));
      acc[rq].z = fmaf(p4.x, v4[0].z, fmaf(p4.y, v4[1].z, fmaf(p4.z, v4[2].z, fmaf(p4.w, v4[3].z, acc[rq].z))));
      acc[rq].w = fmaf(p4.x, v4[0].w, fmaf(p4.y, v4[1].w, fmaf(p4.z, v4[2].w, fmaf(p4.w, v4[3].w, acc[rq].w))));
    }
  }

  __syncthreads();
#pragma unroll
  for (int rq = 0; rq < 4; ++rq)
    *(float4*)&ctx_red[jp][ip + rq * 4][d4 * 4] = acc[rq];
  __syncthreads();

  for (int e = tid; e < 512; e += 256) {
    int r = e >> 5, d = e & 31;
    float sum = 0.f;
#pragma unroll
    for (int p = 0; p < 8; ++p) sum += ctx_red[p][r][d];
    ctx[((size_t)(b * C_ + h * 32 + d)) * S_TOT + i0 + r] = sum;
  }
}

// ---------------------------------------------------------------------------
// Kernel 4: 3x3 SAME conv, 256->256 channels, optional SELU on output.
// grid (128 co-pairs, B), block 256 (16x16 groups of 3x3 pixels).
// ---------------------------------------------------------------------------
template<bool DO_SELU>
__global__ __launch_bounds__(256) void k_conv(const float* __restrict__ in,
                                              const float* __restrict__ Wc,
                                              const float* __restrict__ bias,
                                              float* __restrict__ out) {
  __shared__ float in_s[4][50][52];
  const int tid = threadIdx.x;
  const int co0 = blockIdx.x * 2;
  const int b = blockIdx.y;

  for (int e = tid; e < 4 * 50 * 52; e += 256) ((float*)in_s)[e] = 0.f;

  const int px0 = (tid & 15) * 3;
  const int py0 = (tid >> 4) * 3;
  float acc0[9], acc1[9];
#pragma unroll
  for (int k = 0; k < 9; ++k) { acc0[k] = 0.f; acc1[k] = 0.f; }

  for (int ci0 = 0; ci0 < 256; ci0 += 4) {
    __syncthreads();
#pragma unroll
    for (int cq = 0; cq < 4; ++cq) {
      const float* ip = in + ((size_t)(b * 256 + ci0 + cq)) * S_TOT;
      for (int e = tid; e < 2304; e += 256) {
        int y = e / 48;
        in_s[cq][1 + y][1 + (e - y * 48)] = ip[e];
      }
    }
    __syncthreads();
#pragma unroll
    for (int cq = 0; cq < 4; ++cq) {
      const int ci = ci0 + cq;
      float w0[9], w1[9];
#pragma unroll
      for (int k = 0; k < 9; ++k) {
        w0[k] = Wc[((size_t)co0 * 256 + ci) * 9 + k];
        w1[k] = Wc[((size_t)(co0 + 1) * 256 + ci) * 9 + k];
      }
      float r[5][5];
#pragma unroll
      for (int yy = 0; yy < 5; ++yy)
#pragma unroll
        for (int xx = 0; xx < 5; ++xx)
          r[yy][xx] = in_s[cq][py0 + yy][px0 + xx];
#pragma unroll
      for (int oy = 0; oy < 3; ++oy)
#pragma unroll
        for (int ox = 0; ox < 3; ++ox) {
          float s0 = 0.f, s1 = 0.f;
#pragma unroll
          for (int ky = 0; ky < 3; ++ky)
#pragma unroll
            for (int kx = 0; kx < 3; ++kx) {
              float xv = r[oy + ky][ox + kx];
              s0 = fmaf(xv, w0[ky * 3 + kx], s0);
              s1 = fmaf(xv, w1[ky * 3 + kx], s1);
            }
          acc0[oy * 3 + ox] += s0;
          acc1[oy * 3 + ox] += s1;
        }
    }
  }

  const float b0 = bias[co0], b1 = bias[co0 + 1];
#pragma unroll
  for (int oy = 0; oy < 3; ++oy)
#pragma unroll
    for (int ox = 0; ox < 3; ++ox) {
      float y0 = acc0[oy * 3 + ox] + b0;
      float y1 = acc1[oy * 3 + ox] + b1;
      if (DO_SELU) {
        y0 = 1.0507009873554805f * (y0 > 0.f ? y0 : 1.6732632423543772f * expm1f(y0));
        y1 = 1.0507009873554805f * (y1 > 0.f ? y1 : 1.6732632423543772f * expm1f(y1));
      }
      size_t sp = (size_t)(py0 + oy) * 48 + px0 + ox;
      out[((size_t)(b * 256 + co0)) * S_TOT + sp] = y0;
      out[((size_t)(b * 256 + co0 + 1)) * S_TOT + sp] = y1;
    }
}

// ---------------------------------------------------------------------------
extern "C" void kernel_launch(void* const* d_in, const int* in_sizes, int n_in,
                              void* d_out, int out_size, void* d_ws, size_t ws_size,
                              hipStream_t stream) {
  const float* x   = (const float*)d_in[0];
  const float* ref = (const float*)d_in[1];
  const float* qW1 = (const float*)d_in[2];
  const float* qb1 = (const float*)d_in[3];
  const float* qW2 = (const float*)d_in[4];
  const float* qb2 = (const float*)d_in[5];
  const float* kW1 = (const float*)d_in[6];
  const float* kb1 = (const float*)d_in[7];
  const float* kW2 = (const float*)d_in[8];
  const float* kb2 = (const float*)d_in[9];
  const float* vW1 = (const float*)d_in[10];
  const float* vb1 = (const float*)d_in[11];
  const float* vW2 = (const float*)d_in[12];
  const float* vb2 = (const float*)d_in[13];
  const float* c1W = (const float*)d_in[14];
  const float* c1b = (const float*)d_in[15];
  const float* c2W = (const float*)d_in[16];
  const float* c2b = (const float*)d_in[17];

  float* out = (float*)d_out;
  float* probs = out + (size_t)B_ * C_ * S_TOT;       // [B][H][S][S]
  float* ws = (float*)d_ws;
  const size_t BSC = (size_t)B_ * S_TOT * C_;         // 1,179,648
  const size_t STATS = (size_t)4 * B_ * HEADS_ * S_TOT; // 147,456

  float* Qb  = ws;
  float* Kb  = Qb + BSC;
  float* Vb  = Kb + BSC;
  float* Ht  = Vb + BSC;
  float* stm = Ht + BSC;
  float* stz = stm + STATS;
  float* ctx = stz + STATS;
  float* tmp1 = ctx + BSC;

  dim3 blk(256);
  dim3 gmlp(72, B_);
  k_mlp<0><<<gmlp, blk, 0, stream>>>(x,   qW1, qb1, Ht);
  k_mlp<1><<<gmlp, blk, 0, stream>>>(Ht,  qW2, qb2, Qb);
  k_mlp<0><<<gmlp, blk, 0, stream>>>(ref, kW1, kb1, Ht);
  k_mlp<1><<<gmlp, blk, 0, stream>>>(Ht,  kW2, kb2, Kb);
  k_mlp<0><<<gmlp, blk, 0, stream>>>(ref, vW1, vb1, Ht);
  k_mlp<1><<<gmlp, blk, 0, stream>>>(Ht,  vW2, vb2, Vb);

  k_scores<<<dim3(36, 4, B_), blk, 0, stream>>>(Qb, Kb, probs, stm, stz);
  k_probs_pv<<<dim3(144, 8, B_), blk, 0, stream>>>(Vb, stm, stz, probs, ctx);
  k_conv<true ><<<dim3(128, B_), blk, 0, stream>>>(ctx,  c1W, c1b, tmp1);
  k_conv<false><<<dim3(128, B_), blk, 0, stream>>>(tmp1, c2W, c2b, out);
}

// Round 2
// 1542.513 us; speedup vs baseline: 1.6600x; 1.6600x over previous
//
#include <hip/hip_runtime.h>
#include <hip/hip_bf16.h>

// Problem constants
constexpr int B_ = 2;
constexpr int C_ = 256;
constexpr int S_TOT = 48 * 48;   // 2304
constexpr int HEADS_ = 8;
#define SQRT_DH 5.656854249492380195206754896838f

// ---------------------------------------------------------------------------
// Kernel 1: MLP layer  out[b][s][co] = relu( sum_ci in[b][s][ci]*W[ci][co] + bias[co] )
// IN_MODE 0: in is [B][C][S] (x / ref layout, channel-major)
// IN_MODE 1: in is [B][S][C] (row-major hidden)
// grid (72, B), block 256, 32 s-rows per block, 1 co per thread
// ---------------------------------------------------------------------------
template<int IN_MODE>
__global__ __launch_bounds__(256) void k_mlp(const float* __restrict__ in,
                                             const float* __restrict__ Wm,
                                             const float* __restrict__ bias,
                                             float* __restrict__ out) {
  __shared__ __align__(16) float in_s[32][260];
  const int tid = threadIdx.x;
  const int s0 = blockIdx.x * 32;
  const int b  = blockIdx.y;

  if (IN_MODE == 0) {
    for (int idx = tid; idx < 32 * 256; idx += 256) {
      int ci = idx >> 5, r = idx & 31;
      in_s[r][ci] = in[((size_t)b * C_ + ci) * S_TOT + s0 + r];
    }
  } else {
    for (int idx = tid; idx < 32 * 256; idx += 256) {
      int r = idx >> 8, ci = idx & 255;
      in_s[r][ci] = in[((size_t)b * S_TOT + s0 + r) * C_ + ci];
    }
  }
  __syncthreads();

  const int co = tid;
  float acc[32];
#pragma unroll
  for (int r = 0; r < 32; ++r) acc[r] = 0.f;

  for (int c4 = 0; c4 < 64; ++c4) {
    const float w0 = Wm[(c4 * 4 + 0) * C_ + co];
    const float w1 = Wm[(c4 * 4 + 1) * C_ + co];
    const float w2 = Wm[(c4 * 4 + 2) * C_ + co];
    const float w3 = Wm[(c4 * 4 + 3) * C_ + co];
#pragma unroll
    for (int r = 0; r < 32; ++r) {
      float4 a = *(const float4*)&in_s[r][c4 * 4];
      acc[r] = fmaf(a.x, w0, fmaf(a.y, w1, fmaf(a.z, w2, fmaf(a.w, w3, acc[r]))));
    }
  }

  const float bi = bias[co];
#pragma unroll 4
  for (int r = 0; r < 32; ++r) {
    out[((size_t)b * S_TOT + s0 + r) * C_ + co] = fmaxf(acc[r] + bi, 0.f);
  }
}

// ---------------------------------------------------------------------------
// Kernel 2: fused scores = (Q.K^T)/sqrt(dh) for all 8 heads, top-1-over-heads
// masking, masked-score write to probs region, online per-row softmax stats.
// grid (36 i-tiles, 4 j-chunks, B), block 256, 64x64 tile, micro 4x4/thread.
// ---------------------------------------------------------------------------
__global__ __launch_bounds__(256, 1) void k_scores(const float* __restrict__ Qp,
                                                   const float* __restrict__ Kp,
                                                   float* __restrict__ probs,
                                                   float* __restrict__ st_m,
                                                   float* __restrict__ st_z) {
  __shared__ __align__(16) float q_s[64 * 256];
  __shared__ __align__(16) float k_s[64 * 256];
  const int tid = threadIdx.x;
  const int i0 = blockIdx.x * 64;
  const int js = blockIdx.y;          // 0..3, chunk of 576 j's
  const int b  = blockIdx.z;
  const int jbase = js * 576;
  const int iq = tid >> 4;            // 0..15
  const int jq = tid & 15;            // 0..15

  // stage Q tile (swizzled: float4 unit c4 -> c4 ^ (row&7))
  for (int idx = tid; idx < 64 * 64; idx += 256) {
    int r = idx >> 6, c4 = idx & 63;
    float4 v = *(const float4*)(Qp + ((size_t)b * S_TOT + i0 + r) * C_ + c4 * 4);
    *(float4*)&q_s[r * 256 + ((c4 ^ (r & 7)) << 2)] = v;
  }

  float m_st[4][8], z_st[4][8];
#pragma unroll
  for (int v = 0; v < 4; ++v)
#pragma unroll
    for (int h = 0; h < 8; ++h) { m_st[v][h] = -1e18f; z_st[v][h] = 0.f; }

  for (int jt = 0; jt < 9; ++jt) {
    const int j0 = jbase + jt * 64;
    __syncthreads();
    for (int idx = tid; idx < 64 * 64; idx += 256) {
      int r = idx >> 6, c4 = idx & 63;
      float4 v = *(const float4*)(Kp + ((size_t)b * S_TOT + j0 + r) * C_ + c4 * 4);
      *(float4*)&k_s[r * 256 + ((c4 ^ (r & 7)) << 2)] = v;
    }
    __syncthreads();

    float sacc[4][4][8];
#pragma unroll
    for (int v = 0; v < 4; ++v)
#pragma unroll
      for (int u = 0; u < 4; ++u)
#pragma unroll
        for (int h = 0; h < 8; ++h) sacc[v][u][h] = 0.f;

#pragma unroll
    for (int h = 0; h < 8; ++h) {
#pragma unroll
      for (int cc = 0; cc < 8; ++cc) {
        const int c4g = h * 8 + cc;
        float4 qv[4], kv[4];
#pragma unroll
        for (int v = 0; v < 4; ++v) {
          int r = iq + 16 * v;
          qv[v] = *(const float4*)&q_s[r * 256 + ((c4g ^ (r & 7)) << 2)];
        }
#pragma unroll
        for (int u = 0; u < 4; ++u) {
          int r = jq + 16 * u;
          kv[u] = *(const float4*)&k_s[r * 256 + ((c4g ^ (r & 7)) << 2)];
        }
#pragma unroll
        for (int v = 0; v < 4; ++v)
#pragma unroll
          for (int u = 0; u < 4; ++u) {
            sacc[v][u][h] = fmaf(qv[v].x, kv[u].x,
                             fmaf(qv[v].y, kv[u].y,
                               fmaf(qv[v].z, kv[u].z,
                                 fmaf(qv[v].w, kv[u].w, sacc[v][u][h]))));
          }
      }
    }

    // epilogue: scale, head-max threshold, mask, store, online stats
#pragma unroll
    for (int v = 0; v < 4; ++v) {
      const int i = i0 + iq + 16 * v;
#pragma unroll
      for (int u = 0; u < 4; ++u) {
        const int j = j0 + jq + 16 * u;
        float sc[8];
        float thr = -1e30f;
#pragma unroll
        for (int h = 0; h < 8; ++h) {
          sc[h] = sacc[v][u][h] / SQRT_DH;
          thr = fmaxf(thr, sc[h]);
        }
#pragma unroll
        for (int h = 0; h < 8; ++h) {
          float mv = sc[h] < thr ? -1e18f : sc[h];
          probs[((size_t)((b * 8 + h) * S_TOT + i)) * S_TOT + j] = mv;
          float om = m_st[v][h];
          float nm = fmaxf(om, mv);
          z_st[v][h] = fmaf(z_st[v][h], __expf(om - nm), __expf(mv - nm));
          m_st[v][h] = nm;
        }
      }
    }
  }

  // reduce stats across the 16 jq lanes
#pragma unroll
  for (int v = 0; v < 4; ++v) {
#pragma unroll
    for (int h = 0; h < 8; ++h) {
      float m = m_st[v][h], z = z_st[v][h];
#pragma unroll
      for (int off = 8; off >= 1; off >>= 1) {
        float m2 = __shfl_xor(m, off, 16);
        float z2 = __shfl_xor(z, off, 16);
        float nm = fmaxf(m, m2);
        z = fmaf(z, __expf(m - nm), z2 * __expf(m2 - nm));
        m = nm;
      }
      if (jq == 0) {
        const int i = i0 + iq + 16 * v;
        size_t sidx = ((size_t)(js * B_ + b) * HEADS_ + h) * S_TOT + i;
        st_m[sidx] = m;
        st_z[sidx] = z;
      }
    }
  }
}

// ---------------------------------------------------------------------------
// Kernel 3: finalize probs = exp(s - m)/Z (in-place), ctx = probs @ V.
// grid (144 i-tiles, 8 heads, B), block 256.
// ---------------------------------------------------------------------------
__global__ __launch_bounds__(256) void k_probs_pv(const float* __restrict__ Vp,
                                                  const float* __restrict__ st_m,
                                                  const float* __restrict__ st_z,
                                                  float* __restrict__ probs,
                                                  float* __restrict__ ctx) {
  __shared__ __align__(16) float v_s[32][36];
  __shared__ __align__(16) float p_s[16][36];
  __shared__ float row_m[16], row_iz[16];
  __shared__ __align__(16) float ctx_red[8][16][32];
  const int tid = threadIdx.x;
  const int i0 = blockIdx.x * 16;
  const int h  = blockIdx.y;
  const int b  = blockIdx.z;

  if (tid < 16) {
    const int i = i0 + tid;
    float mm[4], zz[4];
#pragma unroll
    for (int js = 0; js < 4; ++js) {
      size_t sidx = ((size_t)(js * B_ + b) * HEADS_ + h) * S_TOT + i;
      mm[js] = st_m[sidx];
      zz[js] = st_z[sidx];
    }
    float M = fmaxf(fmaxf(mm[0], mm[1]), fmaxf(mm[2], mm[3]));
    float Z = zz[0] * __expf(mm[0] - M) + zz[1] * __expf(mm[1] - M) +
              zz[2] * __expf(mm[2] - M) + zz[3] * __expf(mm[3] - M);
    row_m[tid] = M;
    row_iz[tid] = 1.0f / Z;
  }
  __syncthreads();

  const int il = tid >> 5;        // phase A: 0..7
  const int jl = tid & 31;
  const int d4 = tid & 7;         // phase B
  const int ip = (tid >> 3) & 3;
  const int jp = tid >> 5;        // 0..7

  float4 acc[4];
#pragma unroll
  for (int r = 0; r < 4; ++r) acc[r] = make_float4(0.f, 0.f, 0.f, 0.f);

  float* pbase = probs + ((size_t)(b * 8 + h) * S_TOT + i0) * S_TOT;
  const float* vbase = Vp + (size_t)b * S_TOT * C_ + h * 32;

  for (int j0 = 0; j0 < S_TOT; j0 += 32) {
    __syncthreads();
#pragma unroll
    for (int k = 0; k < 4; ++k) {
      int e = tid + k * 256;
      int r = e >> 5, d = e & 31;
      v_s[r][d] = vbase[(size_t)(j0 + r) * C_ + d];
    }
#pragma unroll
    for (int rr = 0; rr < 2; ++rr) {
      int r = il + rr * 8;
      size_t off = (size_t)r * S_TOT + j0 + jl;
      float sv = pbase[off];
      float p = __expf(sv - row_m[r]) * row_iz[r];
      pbase[off] = p;
      p_s[r][jl] = p;
    }
    __syncthreads();
    float4 v4[4];
#pragma unroll
    for (int jj = 0; jj < 4; ++jj) v4[jj] = *(const float4*)&v_s[jp * 4 + jj][d4 * 4];
#pragma unroll
    for (int rq = 0; rq < 4; ++rq) {
      int r = ip + rq * 4;
      float4 p4 = *(const float4*)&p_s[r][jp * 4];
      acc[rq].x = fmaf(p4.x, v4[0].x, fmaf(p4.y, v4[1].x, fmaf(p4.z, v4[2].x, fmaf(p4.w, v4[3].x, acc[rq].x))));
      acc[rq].y = fmaf(p4.x, v4[0].y, fmaf(p4.y, v4[1].y, fmaf(p4.z, v4[2].y, fmaf(p4.w, v4[3].y, acc[rq].y))));
      acc[rq].z = fmaf(p4.x, v4[0].z, fmaf(p4.y, v4[1].z, fmaf(p4.z, v4[2].z, fmaf(p4.w, v4[3].z, acc[rq].z))));
      acc[rq].w = fmaf(p4.x, v4[0].w, fmaf(p4.y, v4[1].w, fmaf(p4.z, v4[2].w, fmaf(p4.w, v4[3].w, acc[rq].w))));
    }
  }

  __syncthreads();
#pragma unroll
  for (int rq = 0; rq < 4; ++rq)
    *(float4*)&ctx_red[jp][ip + rq * 4][d4 * 4] = acc[rq];
  __syncthreads();

  for (int e = tid; e < 512; e += 256) {
    int r = e >> 5, d = e & 31;
    float sum = 0.f;
#pragma unroll
    for (int p = 0; p < 8; ++p) sum += ctx_red[p][r][d];
    ctx[((size_t)(b * C_ + h * 32 + d)) * S_TOT + i0 + r] = sum;
  }
}

// ---------------------------------------------------------------------------
// Kernel 4a: repack conv weights W[co][ci][3][3] -> Wt[ci][k][co]
// grid (256 ci, 9 k), block 256 (co)
// ---------------------------------------------------------------------------
__global__ __launch_bounds__(256) void k_repackW(const float* __restrict__ W,
                                                 float* __restrict__ Wt) {
  const int ci = blockIdx.x;
  const int k  = blockIdx.y;
  const int co = threadIdx.x;
  Wt[((size_t)ci * 9 + k) * 256 + co] = W[((size_t)co * 256 + ci) * 9 + k];
}

// ---------------------------------------------------------------------------
// Kernel 4b: 3x3 SAME conv, register micro-tile 4co x 6px per thread.
// Block tile: 64 co x 96 px (2 rows of 48). grid (4 co-tiles, 24 row-pairs, B).
// Wave-uniform col-group parity -> static tap indexing (DELTA template).
// W staged in LDS as [ci8][k9][co64] (conflict-free both sides),
// input staged as [ci8][4 rows][56] (image col c at LDS col 4+c, zero halos).
// ---------------------------------------------------------------------------
template<int DELTA>
__device__ __forceinline__ void conv_inner(const float* __restrict__ w_s,
                                           const float (*__restrict__ in_s)[4][56],
                                           int cog, int colg, int row_t,
                                           float (&acc)[4][6]) {
  const int a0 = 6 * colg + 3 - DELTA;   // 16B-aligned LDS col base
#pragma unroll
  for (int ci = 0; ci < 8; ++ci) {
    float4 wv[9];
#pragma unroll
    for (int k = 0; k < 9; ++k)
      wv[k] = *(const float4*)&w_s[(ci * 9 + k) * 64 + cog * 4];
    float rr[3][12];
#pragma unroll
    for (int r = 0; r < 3; ++r) {
      *(float4*)&rr[r][0] = *(const float4*)&in_s[ci][row_t + r][a0];
      *(float4*)&rr[r][4] = *(const float4*)&in_s[ci][row_t + r][a0 + 4];
      *(float4*)&rr[r][8] = *(const float4*)&in_s[ci][row_t + r][a0 + 8];
    }
#pragma unroll
    for (int ky = 0; ky < 3; ++ky)
#pragma unroll
      for (int kx = 0; kx < 3; ++kx) {
        float4 wk = wv[ky * 3 + kx];
#pragma unroll
        for (int p = 0; p < 6; ++p) {
          float xv = rr[ky][DELTA + p + kx];
          acc[0][p] = fmaf(xv, wk.x, acc[0][p]);
          acc[1][p] = fmaf(xv, wk.y, acc[1][p]);
          acc[2][p] = fmaf(xv, wk.z, acc[2][p]);
          acc[3][p] = fmaf(xv, wk.w, acc[3][p]);
        }
      }
  }
}

template<bool DO_SELU>
__global__ __launch_bounds__(256) void k_conv2(const float* __restrict__ in,
                                               const float* __restrict__ Wt,
                                               const float* __restrict__ bias,
                                               float* __restrict__ out) {
  __shared__ __align__(16) float w_s[8 * 9 * 64];      // 18.4 KB
  __shared__ __align__(16) float in_s[8][4][56];       // 7.2 KB
  const int tid  = threadIdx.x;
  const int w    = tid >> 6;          // wave 0..3
  const int lane = tid & 63;
  const int cog   = lane & 15;                       // 16 co-groups of 4
  const int colg  = ((lane >> 4) << 1) | (w & 1);    // 0..7 (parity wave-uniform)
  const int row_t = w >> 1;                          // 0..1
  const int co0 = blockIdx.x * 64;
  const int r0  = blockIdx.y * 2;
  const int b   = blockIdx.z;

  // zero halo cols (0..3 never fully written; 52..55 never written)
  for (int e = tid; e < 8 * 4 * 8; e += 256) {
    int ci = e >> 5, r = (e >> 3) & 3, c = e & 7;
    in_s[ci][r][c < 4 ? c : 48 + c] = 0.f;
  }

  float acc[4][6];
#pragma unroll
  for (int q = 0; q < 4; ++q)
#pragma unroll
    for (int p = 0; p < 6; ++p) acc[q][p] = 0.f;

  for (int ci0 = 0; ci0 < 256; ci0 += 8) {
    __syncthreads();
    // stage W: [ci8][k9][co64] <- Wt[ci0+ci][k][co0+co] (float4, coalesced, conflict-free)
    for (int e = tid; e < 1152; e += 256) {
      int co4 = e & 15; int t = e >> 4; int k = t % 9; int ci = t / 9;
      float4 v = *(const float4*)(Wt + (((size_t)(ci0 + ci) * 9 + k) * 256 + co0 + co4 * 4));
      *(float4*)&w_s[(ci * 9 + k) * 64 + co4 * 4] = v;
    }
    // stage input rows r0-1 .. r0+2 (zero outside image)
    for (int e = tid; e < 384; e += 256) {
      int q = e % 12; int r = (e / 12) & 3; int ci = e / 48;
      int gr = r0 - 1 + r;
      float4 v = make_float4(0.f, 0.f, 0.f, 0.f);
      if (gr >= 0 && gr < 48)
        v = *(const float4*)(in + ((size_t)(b * 256 + ci0 + ci) * 48 + gr) * 48 + 4 * q);
      *(float4*)&in_s[ci][r][4 + 4 * q] = v;
    }
    __syncthreads();
    if (w & 1) conv_inner<1>(w_s, in_s, cog, colg, row_t, acc);
    else       conv_inner<3>(w_s, in_s, cog, colg, row_t, acc);
  }

  const int orow = r0 + row_t;
  const int ocol0 = colg * 6;
#pragma unroll
  for (int q = 0; q < 4; ++q) {
    const int co = co0 + cog * 4 + q;
    const float bi = bias[co];
    float* op = out + ((size_t)(b * 256 + co) * 48 + orow) * 48 + ocol0;
#pragma unroll
    for (int p = 0; p < 6; ++p) {
      float y = acc[q][p] + bi;
      if (DO_SELU)
        y = 1.0507009873554805f * (y > 0.f ? y : 1.6732632423543772f * expm1f(y));
      op[p] = y;
    }
  }
}

// ---------------------------------------------------------------------------
extern "C" void kernel_launch(void* const* d_in, const int* in_sizes, int n_in,
                              void* d_out, int out_size, void* d_ws, size_t ws_size,
                              hipStream_t stream) {
  const float* x   = (const float*)d_in[0];
  const float* ref = (const float*)d_in[1];
  const float* qW1 = (const float*)d_in[2];
  const float* qb1 = (const float*)d_in[3];
  const float* qW2 = (const float*)d_in[4];
  const float* qb2 = (const float*)d_in[5];
  const float* kW1 = (const float*)d_in[6];
  const float* kb1 = (const float*)d_in[7];
  const float* kW2 = (const float*)d_in[8];
  const float* kb2 = (const float*)d_in[9];
  const float* vW1 = (const float*)d_in[10];
  const float* vb1 = (const float*)d_in[11];
  const float* vW2 = (const float*)d_in[12];
  const float* vb2 = (const float*)d_in[13];
  const float* c1W = (const float*)d_in[14];
  const float* c1b = (const float*)d_in[15];
  const float* c2W = (const float*)d_in[16];
  const float* c2b = (const float*)d_in[17];

  float* out = (float*)d_out;
  float* probs = out + (size_t)B_ * C_ * S_TOT;       // [B][H][S][S]
  float* ws = (float*)d_ws;
  const size_t BSC = (size_t)B_ * S_TOT * C_;         // 1,179,648
  const size_t STATS = (size_t)4 * B_ * HEADS_ * S_TOT;
  const size_t WTSZ = (size_t)256 * 9 * 256;          // 589,824

  float* Qb  = ws;
  float* Kb  = Qb + BSC;
  float* Vb  = Kb + BSC;
  float* Ht  = Vb + BSC;
  float* stm = Ht + BSC;
  float* stz = stm + STATS;
  float* ctx = stz + STATS;
  float* tmp1 = ctx + BSC;
  float* Wt1 = tmp1 + BSC;
  float* Wt2 = Wt1 + WTSZ;

  dim3 blk(256);
  k_repackW<<<dim3(256, 9), blk, 0, stream>>>(c1W, Wt1);
  k_repackW<<<dim3(256, 9), blk, 0, stream>>>(c2W, Wt2);

  dim3 gmlp(72, B_);
  k_mlp<0><<<gmlp, blk, 0, stream>>>(x,   qW1, qb1, Ht);
  k_mlp<1><<<gmlp, blk, 0, stream>>>(Ht,  qW2, qb2, Qb);
  k_mlp<0><<<gmlp, blk, 0, stream>>>(ref, kW1, kb1, Ht);
  k_mlp<1><<<gmlp, blk, 0, stream>>>(Ht,  kW2, kb2, Kb);
  k_mlp<0><<<gmlp, blk, 0, stream>>>(ref, vW1, vb1, Ht);
  k_mlp<1><<<gmlp, blk, 0, stream>>>(Ht,  vW2, vb2, Vb);

  k_scores<<<dim3(36, 4, B_), blk, 0, stream>>>(Qb, Kb, probs, stm, stz);
  k_probs_pv<<<dim3(144, 8, B_), blk, 0, stream>>>(Vb, stm, stz, probs, ctx);
  k_conv2<true ><<<dim3(4, 24, B_), blk, 0, stream>>>(ctx,  Wt1, c1b, tmp1);
  k_conv2<false><<<dim3(4, 24, B_), blk, 0, stream>>>(tmp1, Wt2, c2b, out);
}